// Round 9
// baseline (353.294 us; speedup 1.0000x reference)
//
#include <hip/hip_runtime.h>
#include <hip/hip_bf16.h>
#include <math.h>

// ConvNeXt MLP + parallel MoE-LoRA, fp32 in/out, bf16-tolerance harness.
// B,H,W,C = 64,14,14,768 ; N_tok = 12544 = 98*128 ; HID = 3072 ; E=8,K=2,R=16.
//
//   h  = gelu(x @ w1 + b1)                GEMM1  [12544,768]x[768,3072]
//   sd = wt * gelu(x @ wdown)             GEMMd  [12544,768]x[768,128]
//   out = [h | sd] @ [w2 ; wup] + b2      GEMM2  [12544,3200]x[3200,768]
//
// R9 = R8 (proven config: separate kernels, BK=32, 64-B LDS row stride,
//     width-24 grid for GEMM1 [B-strip blocks share bx%8 -> same XCD L2],
//     624-block XCD-swizzled GEMM2, fused prep) + NON-TEMPORAL stores for
//     all streaming outputs (Ap, out). R8 counters: GEMM1 FETCH 84 MB vs
//     24 MB cold inputs -> Ap write stream evicts inputs from L2/L3, so
//     per-kt global_load_lds drains pay HBM latency. nt stores keep the
//     working set cache-resident.

#define NTOK   12544
#define CDIM   768
#define HIDDIM 3072
#define KBIG   3200

typedef __attribute__((ext_vector_type(8))) short bf16x8;
typedef __attribute__((ext_vector_type(4))) float f32x4;

#define GLOBAL_AS(p) ((const __attribute__((address_space(1))) void*)(p))
#define LDS_AS(p)    ((__attribute__((address_space(3))) void*)(p))

__device__ inline unsigned short f2bf(float f) {
    unsigned int x = __float_as_uint(f);
    x += 0x7fffu + ((x >> 16) & 1u);   // RNE
    return (unsigned short)(x >> 16);
}

// tanh-form GELU, branch-free; max |err| ~4.3e-4 vs exact erf form.
__device__ inline float gelu_fast(float x) {
    float x3 = x * x * x;
    float u2 = 1.5957691216057308f * x + 0.07135481627260025f * x3;
    float e = __expf(-u2);
    return x * __builtin_amdgcn_rcpf(1.0f + e);
}

// ---------------- fused prep: cast_x + 3 transposes + pack_wdown ----------------
__global__ void __launch_bounds__(256) prep_kernel(
        const float* __restrict__ x, const float* __restrict__ w1,
        const float* __restrict__ w2, const float* __restrict__ wup,
        const float* __restrict__ wdn,
        unsigned short* __restrict__ xb, unsigned short* __restrict__ w1t,
        unsigned short* __restrict__ B2t, unsigned short* __restrict__ wdt) {
    __shared__ float tile[32][33];
    const int b = blockIdx.x, tid = threadIdx.x;
    if (b < 9408) {                      // cast x -> bf16, float4->ushort4
        int i = b * 256 + tid;
        float4 v = ((const float4*)x)[i];
        ushort4 o;
        o.x = f2bf(v.x); o.y = f2bf(v.y); o.z = f2bf(v.z); o.w = f2bf(v.w);
        ((ushort4*)xb)[i] = o;
        return;
    }
    if (b < 14112) {                     // 32x32 transpose tiles
        const float* in; unsigned short* outp; int Ccols, out_ld, out_off, bx, by;
        if (b < 11712) { int t = b - 9408;  in = w1;  outp = w1t; Ccols = 3072; out_ld = 768;  out_off = 0;    bx = t % 96; by = t / 96; }
        else if (b < 14016) { int t = b - 11712; in = w2;  outp = B2t; Ccols = 768;  out_ld = 3200; out_off = 0;    bx = t % 24; by = t / 24; }
        else { int t = b - 14016; in = wup; outp = B2t; Ccols = 768;  out_ld = 3200; out_off = 3072; bx = t % 24; by = t / 24; }
        int c0 = bx * 32, r0 = by * 32;
        int tx = tid & 31, ty = tid >> 5;
        for (int i = ty; i < 32; i += 8)
            tile[i][tx] = in[(size_t)(r0 + i) * Ccols + c0 + tx];
        __syncthreads();
        for (int i = ty; i < 32; i += 8)
            outp[(size_t)(c0 + i) * out_ld + out_off + r0 + tx] = f2bf(tile[tx][i]);
        return;
    }
    {   // pack_wdown: wdt[j][c] = wdown[e][c][r], j = e*16+r
        int idx = (b - 14112) * 256 + tid;
        int j = idx / 768, c = idx - j * 768;
        int e = j >> 4, r = j & 15;
        wdt[idx] = f2bf(wdn[((size_t)e * 768 + c) * 16 + r]);
    }
}

// ---------------- MFMA GEMM, C = A * Bt^T, 128x128 tile, BK=32 (R3/R8 core) ---
// EPI 0: gelu(acc + b1[n]) -> bf16 Ap[m*3200 + n]           (nt store)
// EPI 1: wt[m, n>>4]*gelu(acc) -> bf16 Ap[m*3200 + 3072+n]  (nt store)
// EPI 2: acc + b2[n] -> f32 out[m*768 + n]                  (nt store)

template <int EPI>
__global__ void __launch_bounds__(256)
gemm_bt_kernel(const unsigned short* __restrict__ A, int lda,
               const unsigned short* __restrict__ Bt, int ldb,
               int kIters,
               const float* __restrict__ bias,
               unsigned short* __restrict__ apOut,
               float* __restrict__ fOut,
               const int* __restrict__ tki,
               const float* __restrict__ tkp) {
    __shared__ __align__(16) unsigned short As[128 * 32];
    __shared__ __align__(16) unsigned short Bs[128 * 32];

    int bx, by;
    if (EPI == 2) {
        // 624 blocks; same-m-row blocks share L&7 -> same XCD, consecutive.
        int L = blockIdx.x;
        int k = L & 7, t = L >> 3;
        bx = t % 6;
        by = (t / 6) * 8 + k;
        if (by >= NTOK / 128) return;      // block-uniform, pre-barrier safe
    } else {
        bx = blockIdx.x;
        by = blockIdx.y;
    }

    const int tid  = threadIdx.x;
    const int wave = tid >> 6;
    const int lane = tid & 63;
    const int m0 = by * 128;
    const int n0 = bx * 128;
    const int wm = (wave >> 1) * 64;
    const int wn = (wave & 1) * 64;
    const int row16 = lane & 15;
    const int quad  = lane >> 4;
    const int kch   = quad * 8;

    f32x4 acc[4][4] = {};

    // Staging: ci = q*256 + tid covers the 128x32 tile row-major (row=ci>>2,
    // kcol=(ci&3)*8); global source contiguous in lane order; LDS dest =
    // wave-uniform base + lane*16B = &tile[ci*8]. 64-B row stride (2-bank).
    const int r_s = tid >> 2;
    const int c_s = (tid & 3) * 8;
    const size_t aRow0 = (size_t)(m0 + r_s) * lda + c_s;
    const size_t aRow1 = aRow0 + (size_t)64 * lda;
    const size_t bRow0 = (size_t)(n0 + r_s) * ldb + c_s;
    const size_t bRow1 = bRow0 + (size_t)64 * ldb;
    unsigned short* asBase0 = &As[(wave * 64) * 8];
    unsigned short* asBase1 = &As[(256 + wave * 64) * 8];
    unsigned short* bsBase0 = &Bs[(wave * 64) * 8];
    unsigned short* bsBase1 = &Bs[(256 + wave * 64) * 8];

    for (int kt = 0; kt < kIters; ++kt) {
        const int k0 = kt * 32;
        __builtin_amdgcn_global_load_lds(GLOBAL_AS(A + aRow0 + k0), LDS_AS(asBase0), 16, 0, 0);
        __builtin_amdgcn_global_load_lds(GLOBAL_AS(A + aRow1 + k0), LDS_AS(asBase1), 16, 0, 0);
        __builtin_amdgcn_global_load_lds(GLOBAL_AS(Bt + bRow0 + k0), LDS_AS(bsBase0), 16, 0, 0);
        __builtin_amdgcn_global_load_lds(GLOBAL_AS(Bt + bRow1 + k0), LDS_AS(bsBase1), 16, 0, 0);
        __syncthreads();

        bf16x8 af[4], bfr[4];
        #pragma unroll
        for (int mi = 0; mi < 4; ++mi)
            af[mi] = *(const bf16x8*)&As[(wm + mi * 16 + row16) * 32 + kch];
        #pragma unroll
        for (int ni = 0; ni < 4; ++ni)
            bfr[ni] = *(const bf16x8*)&Bs[(wn + ni * 16 + row16) * 32 + kch];

        #pragma unroll
        for (int mi = 0; mi < 4; ++mi)
            #pragma unroll
            for (int ni = 0; ni < 4; ++ni)
                acc[mi][ni] = __builtin_amdgcn_mfma_f32_16x16x32_bf16(
                    af[mi], bfr[ni], acc[mi][ni], 0, 0, 0);
        __syncthreads();
    }

    // epilogue: lane holds col = row16 (+16*ni), rows quad*4 + i.
    // All output stores are NON-TEMPORAL: streaming, never re-read by this
    // kernel — keeps xb/w1t/B2t resident in L2/L3 (R9 change).
    #pragma unroll
    for (int mi = 0; mi < 4; ++mi) {
        #pragma unroll
        for (int i = 0; i < 4; ++i) {
            const int m = m0 + wm + mi * 16 + quad * 4 + i;
            int i0 = 0, i1 = 0; float p0 = 0.f, p1 = 0.f;
            if (EPI == 1) {
                i0 = tki[m * 2]; i1 = tki[m * 2 + 1];
                p0 = tkp[m * 2]; p1 = tkp[m * 2 + 1];
            }
            #pragma unroll
            for (int ni = 0; ni < 4; ++ni) {
                const int ncol = n0 + wn + ni * 16 + row16;
                float v = acc[mi][ni][i];
                if (EPI == 0) {
                    v = gelu_fast(v + bias[ncol]);
                    __builtin_nontemporal_store(f2bf(v), &apOut[(size_t)m * KBIG + ncol]);
                } else if (EPI == 1) {
                    const int e = ncol >> 4;
                    float wt = (i0 == e ? p0 : 0.f) + (i1 == e ? p1 : 0.f);
                    v = gelu_fast(v) * wt;
                    __builtin_nontemporal_store(f2bf(v), &apOut[(size_t)m * KBIG + 3072 + ncol]);
                } else {
                    __builtin_nontemporal_store(v + bias[ncol], &fOut[(size_t)m * CDIM + ncol]);
                }
            }
        }
    }
}

// ---------------- launch ----------------

extern "C" void kernel_launch(void* const* d_in, const int* in_sizes, int n_in,
                              void* d_out, int out_size, void* d_ws, size_t ws_size,
                              hipStream_t stream) {
    const float* x   = (const float*)d_in[0];
    const float* tkp = (const float*)d_in[1];
    const int*   tki = (const int*)d_in[2];
    const float* w1  = (const float*)d_in[3];
    const float* b1  = (const float*)d_in[4];
    const float* w2  = (const float*)d_in[5];
    const float* b2  = (const float*)d_in[6];
    const float* wdn = (const float*)d_in[7];
    const float* wup = (const float*)d_in[8];
    float* out = (float*)d_out;

    unsigned short* xb  = (unsigned short*)d_ws;
    unsigned short* w1t = xb  + (size_t)NTOK * CDIM;      // 3072 x 768
    unsigned short* B2t = w1t + (size_t)HIDDIM * CDIM;    // 768 x 3200
    unsigned short* wdt = B2t + (size_t)CDIM * KBIG;      // 128 x 768
    unsigned short* Ap  = wdt + (size_t)128 * CDIM;       // 12544 x 3200

    prep_kernel<<<dim3(14496), 256, 0, stream>>>(x, w1, w2, wup, wdn,
                                                 xb, w1t, B2t, wdt);

    // GEMMd: sd -> Ap[:, 3072:3200] ; 98 blocks
    gemm_bt_kernel<1><<<dim3(1, NTOK / 128), 256, 0, stream>>>(
        xb, CDIM, wdt, CDIM, CDIM / 32, nullptr, Ap, nullptr, tki, tkp);
    // GEMM1: h -> Ap[:, 0:3072] ; grid (24, 98) — width-24 B-locality preserved
    gemm_bt_kernel<0><<<dim3(HIDDIM / 128, NTOK / 128), 256, 0, stream>>>(
        xb, CDIM, w1t, CDIM, CDIM / 32, b1, Ap, nullptr, nullptr, nullptr);
    // GEMM2: out = Ap @ B2t^T + b2 ; 624-block XCD-swizzled grid
    gemm_bt_kernel<2><<<dim3(624), 256, 0, stream>>>(
        Ap, KBIG, B2t, KBIG, KBIG / 32, b2, nullptr, out, nullptr, nullptr);
}

// Round 10
// 348.034 us; speedup vs baseline: 1.0151x; 1.0151x over previous
//
#include <hip/hip_runtime.h>
#include <hip/hip_bf16.h>
#include <math.h>

// ConvNeXt MLP + parallel MoE-LoRA, fp32 in/out, bf16-tolerance harness.
// B,H,W,C = 64,14,14,768 ; N_tok = 12544 = 98*128 ; HID = 3072 ; E=8,K=2,R=16.
//
//   h  = gelu(x @ w1 + b1)                GEMM1  [12544,768]x[768,3072]
//   sd = wt * gelu(x @ wdown)             GEMMd  [12544,768]x[768,128]
//   out = [h | sd] @ [w2 ; wup] + b2      GEMM2  [12544,3200]x[3200,768]
//
// R10 = R8 config (nt stores of R9 reverted: GEMM2 110->125, FETCH ~same —
//   L2-write-path cost, no eviction win) + two changes:
//   (1) OPERAND-SWAPPED MFMA: acc = mfma(bfr, af, acc) computes the transposed
//       fragment so a lane's 4 regs = 4 consecutive n-cols -> epilogue emits
//       16 packed 8-B stores (bf16) / 16-B float4 stores (fp32) instead of 64
//       scalar 2-B/4-B stores. Short-K kernels (kt=24) are epilogue-heavy.
//   (2) prep transposes: 64x64 tiles, float4 loads + 16-B packed bf16 stores.

#define NTOK   12544
#define CDIM   768
#define HIDDIM 3072
#define KBIG   3200

typedef __attribute__((ext_vector_type(8))) short bf16x8;
typedef __attribute__((ext_vector_type(4))) float f32x4;

#define GLOBAL_AS(p) ((const __attribute__((address_space(1))) void*)(p))
#define LDS_AS(p)    ((__attribute__((address_space(3))) void*)(p))

__device__ inline unsigned short f2bf(float f) {
    unsigned int x = __float_as_uint(f);
    x += 0x7fffu + ((x >> 16) & 1u);   // RNE
    return (unsigned short)(x >> 16);
}

// tanh-form GELU, branch-free; max |err| ~4.3e-4 vs exact erf form.
__device__ inline float gelu_fast(float x) {
    float x3 = x * x * x;
    float u2 = 1.5957691216057308f * x + 0.07135481627260025f * x3;
    float e = __expf(-u2);
    return x * __builtin_amdgcn_rcpf(1.0f + e);
}

// ---------------- fused prep: cast_x + 3 transposes (64x64) + pack_wdown -------
// segments: [0,9408) cast_x | [9408,9984) w1->w1t | [9984,10560) w2->B2t@0
//           [10560,10584) wup->B2t@3072 | [10584,10968) pack_wdown
__global__ void __launch_bounds__(256) prep_kernel(
        const float* __restrict__ x, const float* __restrict__ w1,
        const float* __restrict__ w2, const float* __restrict__ wup,
        const float* __restrict__ wdn,
        unsigned short* __restrict__ xb, unsigned short* __restrict__ w1t,
        unsigned short* __restrict__ B2t, unsigned short* __restrict__ wdt) {
    __shared__ float tile[64][65];
    const int b = blockIdx.x, tid = threadIdx.x;
    if (b < 9408) {                      // cast x -> bf16, float4->ushort4
        int i = b * 256 + tid;
        float4 v = ((const float4*)x)[i];
        ushort4 o;
        o.x = f2bf(v.x); o.y = f2bf(v.y); o.z = f2bf(v.z); o.w = f2bf(v.w);
        ((ushort4*)xb)[i] = o;
        return;
    }
    if (b < 10584) {                     // 64x64 transpose tiles
        const float* in; unsigned short* outp; int Ccols, out_ld, out_off, bx, by;
        if (b < 9984)       { int t = b - 9408;  in = w1;  outp = w1t; Ccols = 3072; out_ld = 768;  out_off = 0;    bx = t % 48; by = t / 48; }
        else if (b < 10560) { int t = b - 9984;  in = w2;  outp = B2t; Ccols = 768;  out_ld = 3200; out_off = 0;    bx = t % 12; by = t / 12; }
        else                { int t = b - 10560; in = wup; outp = B2t; Ccols = 768;  out_ld = 3200; out_off = 3072; bx = t % 12; by = t / 12; }
        const int c0 = bx * 64, r0 = by * 64;
        #pragma unroll
        for (int p = 0; p < 4; ++p) {
            int idx = p * 256 + tid;
            int r = idx >> 4, c4 = (idx & 15) * 4;
            float4 v = *(const float4*)&in[(size_t)(r0 + r) * Ccols + c0 + c4];
            tile[r][c4 + 0] = v.x; tile[r][c4 + 1] = v.y;
            tile[r][c4 + 2] = v.z; tile[r][c4 + 3] = v.w;
        }
        __syncthreads();
        #pragma unroll
        for (int p = 0; p < 2; ++p) {
            int u = p * 256 + tid;
            int cc = u >> 3, r8 = (u & 7) * 8;
            uint4 pk;
            pk.x = (unsigned)f2bf(tile[r8 + 0][cc]) | ((unsigned)f2bf(tile[r8 + 1][cc]) << 16);
            pk.y = (unsigned)f2bf(tile[r8 + 2][cc]) | ((unsigned)f2bf(tile[r8 + 3][cc]) << 16);
            pk.z = (unsigned)f2bf(tile[r8 + 4][cc]) | ((unsigned)f2bf(tile[r8 + 5][cc]) << 16);
            pk.w = (unsigned)f2bf(tile[r8 + 6][cc]) | ((unsigned)f2bf(tile[r8 + 7][cc]) << 16);
            *(uint4*)&outp[(size_t)(c0 + cc) * out_ld + out_off + r0 + r8] = pk;
        }
        return;
    }
    {   // pack_wdown: wdt[j][c] = wdown[e][c][r], j = e*16+r
        int idx = (b - 10584) * 256 + tid;
        int j = idx / 768, c = idx - j * 768;
        int e = j >> 4, r = j & 15;
        wdt[idx] = f2bf(wdn[((size_t)e * 768 + c) * 16 + r]);
    }
}

// ---------------- MFMA GEMM, C = A * Bt^T, 128x128 tile, BK=32 ----------------
// K-loop = R3/R8-proven core; MFMA operands SWAPPED (bfr, af) so the C/D
// fragment is transposed: lane holds m = lane&15, n = quad*4 + reg_i (4
// consecutive columns) -> wide epilogue stores.
// EPI 0: gelu(acc + b1[n]) -> bf16 Ap[m*3200 + n]         (8-B packed stores)
// EPI 1: wt[m, n>>4]*gelu(acc) -> bf16 Ap[m*3200+3072+n]  (8-B packed stores)
// EPI 2: acc + b2[n] -> f32 out[m*768 + n]                (16-B float4 stores)

template <int EPI>
__global__ void __launch_bounds__(256)
gemm_bt_kernel(const unsigned short* __restrict__ A, int lda,
               const unsigned short* __restrict__ Bt, int ldb,
               int kIters,
               const float* __restrict__ bias,
               unsigned short* __restrict__ apOut,
               float* __restrict__ fOut,
               const int* __restrict__ tki,
               const float* __restrict__ tkp) {
    __shared__ __align__(16) unsigned short As[128 * 32];
    __shared__ __align__(16) unsigned short Bs[128 * 32];

    int bx, by;
    if (EPI == 2) {
        // 624 blocks; same-m-row blocks share L&7 -> same XCD, consecutive.
        int L = blockIdx.x;
        int k = L & 7, t = L >> 3;
        bx = t % 6;
        by = (t / 6) * 8 + k;
        if (by >= NTOK / 128) return;      // block-uniform, pre-barrier safe
    } else {
        bx = blockIdx.x;
        by = blockIdx.y;
    }

    const int tid  = threadIdx.x;
    const int wave = tid >> 6;
    const int lane = tid & 63;
    const int m0 = by * 128;
    const int n0 = bx * 128;
    const int wm = (wave >> 1) * 64;
    const int wn = (wave & 1) * 64;
    const int row16 = lane & 15;
    const int quad  = lane >> 4;
    const int kch   = quad * 8;

    f32x4 acc[4][4] = {};

    // Staging: ci = q*256 + tid covers the 128x32 tile row-major (row=ci>>2,
    // kcol=(ci&3)*8); global source contiguous in lane order; LDS dest =
    // wave-uniform base + lane*16B = &tile[ci*8]. 64-B row stride (2-bank).
    const int r_s = tid >> 2;
    const int c_s = (tid & 3) * 8;
    const size_t aRow0 = (size_t)(m0 + r_s) * lda + c_s;
    const size_t aRow1 = aRow0 + (size_t)64 * lda;
    const size_t bRow0 = (size_t)(n0 + r_s) * ldb + c_s;
    const size_t bRow1 = bRow0 + (size_t)64 * ldb;
    unsigned short* asBase0 = &As[(wave * 64) * 8];
    unsigned short* asBase1 = &As[(256 + wave * 64) * 8];
    unsigned short* bsBase0 = &Bs[(wave * 64) * 8];
    unsigned short* bsBase1 = &Bs[(256 + wave * 64) * 8];

    for (int kt = 0; kt < kIters; ++kt) {
        const int k0 = kt * 32;
        __builtin_amdgcn_global_load_lds(GLOBAL_AS(A + aRow0 + k0), LDS_AS(asBase0), 16, 0, 0);
        __builtin_amdgcn_global_load_lds(GLOBAL_AS(A + aRow1 + k0), LDS_AS(asBase1), 16, 0, 0);
        __builtin_amdgcn_global_load_lds(GLOBAL_AS(Bt + bRow0 + k0), LDS_AS(bsBase0), 16, 0, 0);
        __builtin_amdgcn_global_load_lds(GLOBAL_AS(Bt + bRow1 + k0), LDS_AS(bsBase1), 16, 0, 0);
        __syncthreads();

        bf16x8 af[4], bfr[4];
        #pragma unroll
        for (int mi = 0; mi < 4; ++mi)
            af[mi] = *(const bf16x8*)&As[(wm + mi * 16 + row16) * 32 + kch];
        #pragma unroll
        for (int ni = 0; ni < 4; ++ni)
            bfr[ni] = *(const bf16x8*)&Bs[(wn + ni * 16 + row16) * 32 + kch];

        #pragma unroll
        for (int mi = 0; mi < 4; ++mi)
            #pragma unroll
            for (int ni = 0; ni < 4; ++ni)
                acc[mi][ni] = __builtin_amdgcn_mfma_f32_16x16x32_bf16(
                    bfr[ni], af[mi], acc[mi][ni], 0, 0, 0);   // SWAPPED: D^T
        __syncthreads();
    }

    // epilogue (transposed fragment): m = m0+wm+mi*16+row16 ;
    // n = n0+wn+ni*16+quad*4+i  -> reg i spans 4 CONSECUTIVE columns.
    const int nbq = quad * 4;

    float4 b4[4];
    if (EPI != 1) {
        #pragma unroll
        for (int ni = 0; ni < 4; ++ni)
            b4[ni] = *(const float4*)&bias[n0 + wn + ni * 16 + nbq];
    }

    #pragma unroll
    for (int mi = 0; mi < 4; ++mi) {
        const int m = m0 + wm + mi * 16 + row16;
        int i0 = 0, i1 = 0; float p0 = 0.f, p1 = 0.f;
        if (EPI == 1) {
            i0 = tki[m * 2]; i1 = tki[m * 2 + 1];
            p0 = tkp[m * 2]; p1 = tkp[m * 2 + 1];
        }
        #pragma unroll
        for (int ni = 0; ni < 4; ++ni) {
            const int nb = n0 + wn + ni * 16 + nbq;
            float v0 = acc[mi][ni][0], v1 = acc[mi][ni][1];
            float v2 = acc[mi][ni][2], v3 = acc[mi][ni][3];
            if (EPI == 0) {
                v0 = gelu_fast(v0 + b4[ni].x); v1 = gelu_fast(v1 + b4[ni].y);
                v2 = gelu_fast(v2 + b4[ni].z); v3 = gelu_fast(v3 + b4[ni].w);
                uint2 pk;
                pk.x = (unsigned)f2bf(v0) | ((unsigned)f2bf(v1) << 16);
                pk.y = (unsigned)f2bf(v2) | ((unsigned)f2bf(v3) << 16);
                *(uint2*)&apOut[(size_t)m * KBIG + nb] = pk;
            } else if (EPI == 1) {
                const int e = (wn + ni * 16) >> 4;     // n0==0 for GEMMd
                float wt = (i0 == e ? p0 : 0.f) + (i1 == e ? p1 : 0.f);
                v0 = gelu_fast(v0) * wt; v1 = gelu_fast(v1) * wt;
                v2 = gelu_fast(v2) * wt; v3 = gelu_fast(v3) * wt;
                uint2 pk;
                pk.x = (unsigned)f2bf(v0) | ((unsigned)f2bf(v1) << 16);
                pk.y = (unsigned)f2bf(v2) | ((unsigned)f2bf(v3) << 16);
                *(uint2*)&apOut[(size_t)m * KBIG + 3072 + nb] = pk;
            } else {
                float4 o;
                o.x = v0 + b4[ni].x; o.y = v1 + b4[ni].y;
                o.z = v2 + b4[ni].z; o.w = v3 + b4[ni].w;
                *(float4*)&fOut[(size_t)m * CDIM + nb] = o;
            }
        }
    }
}

// ---------------- launch ----------------

extern "C" void kernel_launch(void* const* d_in, const int* in_sizes, int n_in,
                              void* d_out, int out_size, void* d_ws, size_t ws_size,
                              hipStream_t stream) {
    const float* x   = (const float*)d_in[0];
    const float* tkp = (const float*)d_in[1];
    const int*   tki = (const int*)d_in[2];
    const float* w1  = (const float*)d_in[3];
    const float* b1  = (const float*)d_in[4];
    const float* w2  = (const float*)d_in[5];
    const float* b2  = (const float*)d_in[6];
    const float* wdn = (const float*)d_in[7];
    const float* wup = (const float*)d_in[8];
    float* out = (float*)d_out;

    unsigned short* xb  = (unsigned short*)d_ws;
    unsigned short* w1t = xb  + (size_t)NTOK * CDIM;      // 3072 x 768
    unsigned short* B2t = w1t + (size_t)HIDDIM * CDIM;    // 768 x 3200
    unsigned short* wdt = B2t + (size_t)CDIM * KBIG;      // 128 x 768
    unsigned short* Ap  = wdt + (size_t)128 * CDIM;       // 12544 x 3200

    prep_kernel<<<dim3(10968), 256, 0, stream>>>(x, w1, w2, wup, wdn,
                                                 xb, w1t, B2t, wdt);

    // GEMMd: sd -> Ap[:, 3072:3200] ; 98 blocks
    gemm_bt_kernel<1><<<dim3(1, NTOK / 128), 256, 0, stream>>>(
        xb, CDIM, wdt, CDIM, CDIM / 32, nullptr, Ap, nullptr, tki, tkp);
    // GEMM1: h -> Ap[:, 0:3072] ; grid (24, 98) — width-24 B-locality preserved
    gemm_bt_kernel<0><<<dim3(HIDDIM / 128, NTOK / 128), 256, 0, stream>>>(
        xb, CDIM, w1t, CDIM, CDIM / 32, b1, Ap, nullptr, nullptr, nullptr);
    // GEMM2: out = Ap @ B2t^T + b2 ; 624-block XCD-swizzled grid
    gemm_bt_kernel<2><<<dim3(624), 256, 0, stream>>>(
        Ap, KBIG, B2t, KBIG, KBIG / 32, b2, nullptr, out, nullptr, nullptr);
}

// Round 11
// 309.036 us; speedup vs baseline: 1.1432x; 1.1262x over previous
//
#include <hip/hip_runtime.h>
#include <hip/hip_bf16.h>
#include <math.h>

// ConvNeXt MLP + parallel MoE-LoRA, fp32 in/out, bf16-tolerance harness.
// B,H,W,C = 64,14,14,768 ; N_tok = 12544 = 98*128 ; HID = 3072 ; E=8,K=2,R=16.
//
//   h  = gelu(x @ w1 + b1)                GEMM1  [12544,768]x[768,3072]
//   sd = wt * gelu(x @ wdown)             GEMMd  [12544,768]x[768,128]
//   out = [h | sd] @ [w2 ; wup] + b2      GEMM2  [12544,3200]x[3200,768]
//
// R11 = R8 config (R10 operand-swap reverted: per-lane-wide stores broke
//   lane-adjacency coalescing, WRITE 75->87 MB, GEMM1 +9us) + LDS DOUBLE
//   BUFFERING: R8 arithmetic shows ~2400 cyc/kt vs ~300 content — loads were
//   issued after the barrier and consumed immediately (full latency exposed
//   every kt). Now: barrier -> prefetch kt+1 into alt buffer -> compute kt;
//   the next barrier's vmcnt(0) drain waits only residual latency.
//   Epilogue/grids/staging layout identical to R8 (all proven).

#define NTOK   12544
#define CDIM   768
#define HIDDIM 3072
#define KBIG   3200

typedef __attribute__((ext_vector_type(8))) short bf16x8;
typedef __attribute__((ext_vector_type(4))) float f32x4;

#define GLOBAL_AS(p) ((const __attribute__((address_space(1))) void*)(p))
#define LDS_AS(p)    ((__attribute__((address_space(3))) void*)(p))

__device__ inline unsigned short f2bf(float f) {
    unsigned int x = __float_as_uint(f);
    x += 0x7fffu + ((x >> 16) & 1u);   // RNE
    return (unsigned short)(x >> 16);
}

// tanh-form GELU, branch-free; max |err| ~4.3e-4 vs exact erf form.
__device__ inline float gelu_fast(float x) {
    float x3 = x * x * x;
    float u2 = 1.5957691216057308f * x + 0.07135481627260025f * x3;
    float e = __expf(-u2);
    return x * __builtin_amdgcn_rcpf(1.0f + e);
}

// ---------------- fused prep: cast_x + 3 transposes (64x64) + pack_wdown -------
__global__ void __launch_bounds__(256) prep_kernel(
        const float* __restrict__ x, const float* __restrict__ w1,
        const float* __restrict__ w2, const float* __restrict__ wup,
        const float* __restrict__ wdn,
        unsigned short* __restrict__ xb, unsigned short* __restrict__ w1t,
        unsigned short* __restrict__ B2t, unsigned short* __restrict__ wdt) {
    __shared__ float tile[64][65];
    const int b = blockIdx.x, tid = threadIdx.x;
    if (b < 9408) {                      // cast x -> bf16, float4->ushort4
        int i = b * 256 + tid;
        float4 v = ((const float4*)x)[i];
        ushort4 o;
        o.x = f2bf(v.x); o.y = f2bf(v.y); o.z = f2bf(v.z); o.w = f2bf(v.w);
        ((ushort4*)xb)[i] = o;
        return;
    }
    if (b < 10584) {                     // 64x64 transpose tiles
        const float* in; unsigned short* outp; int Ccols, out_ld, out_off, bx, by;
        if (b < 9984)       { int t = b - 9408;  in = w1;  outp = w1t; Ccols = 3072; out_ld = 768;  out_off = 0;    bx = t % 48; by = t / 48; }
        else if (b < 10560) { int t = b - 9984;  in = w2;  outp = B2t; Ccols = 768;  out_ld = 3200; out_off = 0;    bx = t % 12; by = t / 12; }
        else                { int t = b - 10560; in = wup; outp = B2t; Ccols = 768;  out_ld = 3200; out_off = 3072; bx = t % 12; by = t / 12; }
        const int c0 = bx * 64, r0 = by * 64;
        #pragma unroll
        for (int p = 0; p < 4; ++p) {
            int idx = p * 256 + tid;
            int r = idx >> 4, c4 = (idx & 15) * 4;
            float4 v = *(const float4*)&in[(size_t)(r0 + r) * Ccols + c0 + c4];
            tile[r][c4 + 0] = v.x; tile[r][c4 + 1] = v.y;
            tile[r][c4 + 2] = v.z; tile[r][c4 + 3] = v.w;
        }
        __syncthreads();
        #pragma unroll
        for (int p = 0; p < 2; ++p) {
            int u = p * 256 + tid;
            int cc = u >> 3, r8 = (u & 7) * 8;
            uint4 pk;
            pk.x = (unsigned)f2bf(tile[r8 + 0][cc]) | ((unsigned)f2bf(tile[r8 + 1][cc]) << 16);
            pk.y = (unsigned)f2bf(tile[r8 + 2][cc]) | ((unsigned)f2bf(tile[r8 + 3][cc]) << 16);
            pk.z = (unsigned)f2bf(tile[r8 + 4][cc]) | ((unsigned)f2bf(tile[r8 + 5][cc]) << 16);
            pk.w = (unsigned)f2bf(tile[r8 + 6][cc]) | ((unsigned)f2bf(tile[r8 + 7][cc]) << 16);
            *(uint4*)&outp[(size_t)(c0 + cc) * out_ld + out_off + r0 + r8] = pk;
        }
        return;
    }
    {   // pack_wdown: wdt[j][c] = wdown[e][c][r], j = e*16+r
        int idx = (b - 10584) * 256 + tid;
        int j = idx / 768, c = idx - j * 768;
        int e = j >> 4, r = j & 15;
        wdt[idx] = f2bf(wdn[((size_t)e * 768 + c) * 16 + r]);
    }
}

// ------- MFMA GEMM, C = A * Bt^T, 128x128 tile, BK=32, LDS double-buffer ------
// EPI 0: gelu(acc + b1[n]) -> bf16 Ap[m*3200 + n]
// EPI 1: wt[m, n>>4]*gelu(acc) -> bf16 Ap[m*3200 + 3072 + n]
// EPI 2: acc + b2[n] -> f32 out[m*768 + n]  (1-D grid + XCD swizzle)

#define BUFSZ (128 * 32)

template <int EPI>
__global__ void __launch_bounds__(256)
gemm_bt_kernel(const unsigned short* __restrict__ A, int lda,
               const unsigned short* __restrict__ Bt, int ldb,
               int kIters,
               const float* __restrict__ bias,
               unsigned short* __restrict__ apOut,
               float* __restrict__ fOut,
               const int* __restrict__ tki,
               const float* __restrict__ tkp) {
    __shared__ __align__(16) unsigned short As[2 * BUFSZ];
    __shared__ __align__(16) unsigned short Bs[2 * BUFSZ];

    int bx, by;
    if (EPI == 2) {
        // 624 blocks; same-m-row blocks share L&7 -> same XCD, consecutive.
        int L = blockIdx.x;
        int k = L & 7, t = L >> 3;
        bx = t % 6;
        by = (t / 6) * 8 + k;
        if (by >= NTOK / 128) return;      // block-uniform, pre-barrier safe
    } else {
        bx = blockIdx.x;
        by = blockIdx.y;
    }

    const int tid  = threadIdx.x;
    const int wave = tid >> 6;
    const int lane = tid & 63;
    const int m0 = by * 128;
    const int n0 = bx * 128;
    const int wm = (wave >> 1) * 64;
    const int wn = (wave & 1) * 64;
    const int row16 = lane & 15;
    const int quad  = lane >> 4;
    const int kch   = quad * 8;

    f32x4 acc[4][4] = {};

    // Staging (R3/R8-proven): ci = q*256 + tid covers the 128x32 tile
    // row-major (row=ci>>2, kcol=(ci&3)*8); source contiguous in lane order;
    // LDS dest = wave-uniform base + lane*16B. 64-B row stride (2-bank).
    const int r_s = tid >> 2;
    const int c_s = (tid & 3) * 8;
    const size_t aRow0 = (size_t)(m0 + r_s) * lda + c_s;
    const size_t aRow1 = aRow0 + (size_t)64 * lda;
    const size_t bRow0 = (size_t)(n0 + r_s) * ldb + c_s;
    const size_t bRow1 = bRow0 + (size_t)64 * ldb;
    unsigned short* asB0 = &As[(wave * 64) * 8];
    unsigned short* asB1 = &As[(256 + wave * 64) * 8];
    unsigned short* bsB0 = &Bs[(wave * 64) * 8];
    unsigned short* bsB1 = &Bs[(256 + wave * 64) * 8];

    // prologue: prefetch tile 0 into buffer 0
    {
        __builtin_amdgcn_global_load_lds(GLOBAL_AS(A + aRow0), LDS_AS(asB0), 16, 0, 0);
        __builtin_amdgcn_global_load_lds(GLOBAL_AS(A + aRow1), LDS_AS(asB1), 16, 0, 0);
        __builtin_amdgcn_global_load_lds(GLOBAL_AS(Bt + bRow0), LDS_AS(bsB0), 16, 0, 0);
        __builtin_amdgcn_global_load_lds(GLOBAL_AS(Bt + bRow1), LDS_AS(bsB1), 16, 0, 0);
    }

    for (int kt = 0; kt < kIters; ++kt) {
        // barrier: compiler emits vmcnt(0)+lgkmcnt(0) drain — guarantees
        // buf[kt&1] loads landed AND all waves done reading buf[(kt+1)&1].
        __syncthreads();

        // prefetch kt+1 into the alternate buffer; in flight during compute
        if (kt + 1 < kIters) {
            const int k1 = (kt + 1) * 32;
            const int po = ((kt + 1) & 1) * BUFSZ;
            __builtin_amdgcn_global_load_lds(GLOBAL_AS(A + aRow0 + k1), LDS_AS(asB0 + po), 16, 0, 0);
            __builtin_amdgcn_global_load_lds(GLOBAL_AS(A + aRow1 + k1), LDS_AS(asB1 + po), 16, 0, 0);
            __builtin_amdgcn_global_load_lds(GLOBAL_AS(Bt + bRow0 + k1), LDS_AS(bsB0 + po), 16, 0, 0);
            __builtin_amdgcn_global_load_lds(GLOBAL_AS(Bt + bRow1 + k1), LDS_AS(bsB1 + po), 16, 0, 0);
        }

        const int co = (kt & 1) * BUFSZ;
        bf16x8 af[4], bfr[4];
        #pragma unroll
        for (int mi = 0; mi < 4; ++mi)
            af[mi] = *(const bf16x8*)&As[co + (wm + mi * 16 + row16) * 32 + kch];
        #pragma unroll
        for (int ni = 0; ni < 4; ++ni)
            bfr[ni] = *(const bf16x8*)&Bs[co + (wn + ni * 16 + row16) * 32 + kch];

        #pragma unroll
        for (int mi = 0; mi < 4; ++mi)
            #pragma unroll
            for (int ni = 0; ni < 4; ++ni)
                acc[mi][ni] = __builtin_amdgcn_mfma_f32_16x16x32_bf16(
                    af[mi], bfr[ni], acc[mi][ni], 0, 0, 0);
    }

    // epilogue (R8-exact): lane holds col = row16 (+16*ni), rows quad*4 + i
    #pragma unroll
    for (int mi = 0; mi < 4; ++mi) {
        #pragma unroll
        for (int i = 0; i < 4; ++i) {
            const int m = m0 + wm + mi * 16 + quad * 4 + i;
            int i0 = 0, i1 = 0; float p0 = 0.f, p1 = 0.f;
            if (EPI == 1) {
                i0 = tki[m * 2]; i1 = tki[m * 2 + 1];
                p0 = tkp[m * 2]; p1 = tkp[m * 2 + 1];
            }
            #pragma unroll
            for (int ni = 0; ni < 4; ++ni) {
                const int ncol = n0 + wn + ni * 16 + row16;
                float v = acc[mi][ni][i];
                if (EPI == 0) {
                    v = gelu_fast(v + bias[ncol]);
                    apOut[(size_t)m * KBIG + ncol] = f2bf(v);
                } else if (EPI == 1) {
                    const int e = ncol >> 4;
                    float wt = (i0 == e ? p0 : 0.f) + (i1 == e ? p1 : 0.f);
                    v = gelu_fast(v) * wt;
                    apOut[(size_t)m * KBIG + 3072 + ncol] = f2bf(v);
                } else {
                    fOut[(size_t)m * CDIM + ncol] = v + bias[ncol];
                }
            }
        }
    }
}

// ---------------- launch ----------------

extern "C" void kernel_launch(void* const* d_in, const int* in_sizes, int n_in,
                              void* d_out, int out_size, void* d_ws, size_t ws_size,
                              hipStream_t stream) {
    const float* x   = (const float*)d_in[0];
    const float* tkp = (const float*)d_in[1];
    const int*   tki = (const int*)d_in[2];
    const float* w1  = (const float*)d_in[3];
    const float* b1  = (const float*)d_in[4];
    const float* w2  = (const float*)d_in[5];
    const float* b2  = (const float*)d_in[6];
    const float* wdn = (const float*)d_in[7];
    const float* wup = (const float*)d_in[8];
    float* out = (float*)d_out;

    unsigned short* xb  = (unsigned short*)d_ws;
    unsigned short* w1t = xb  + (size_t)NTOK * CDIM;      // 3072 x 768
    unsigned short* B2t = w1t + (size_t)HIDDIM * CDIM;    // 768 x 3200
    unsigned short* wdt = B2t + (size_t)CDIM * KBIG;      // 128 x 768
    unsigned short* Ap  = wdt + (size_t)128 * CDIM;       // 12544 x 3200

    prep_kernel<<<dim3(10968), 256, 0, stream>>>(x, w1, w2, wup, wdn,
                                                 xb, w1t, B2t, wdt);

    // GEMMd: sd -> Ap[:, 3072:3200] ; 98 blocks
    gemm_bt_kernel<1><<<dim3(1, NTOK / 128), 256, 0, stream>>>(
        xb, CDIM, wdt, CDIM, CDIM / 32, nullptr, Ap, nullptr, tki, tkp);
    // GEMM1: h -> Ap[:, 0:3072] ; grid (24, 98) — width-24 B-locality preserved
    gemm_bt_kernel<0><<<dim3(HIDDIM / 128, NTOK / 128), 256, 0, stream>>>(
        xb, CDIM, w1t, CDIM, CDIM / 32, b1, Ap, nullptr, nullptr, nullptr);
    // GEMM2: out = Ap @ B2t^T + b2 ; 624-block XCD-swizzled grid
    gemm_bt_kernel<2><<<dim3(624), 256, 0, stream>>>(
        Ap, KBIG, B2t, KBIG, KBIG / 32, b2, nullptr, out, nullptr, nullptr);
}

// Round 12
// 305.640 us; speedup vs baseline: 1.1559x; 1.0111x over previous
//
#include <hip/hip_runtime.h>
#include <hip/hip_bf16.h>
#include <math.h>

// ConvNeXt MLP + parallel MoE-LoRA, fp32 in/out, bf16-tolerance harness.
// B,H,W,C = 64,14,14,768 ; N_tok = 12544 = 98*128 ; HID = 3072 ; E=8,K=2,R=16.
//
//   h  = gelu(x @ w1 + b1)                GEMM1  [12544,768]x[768,3072]
//   sd = wt * gelu(x @ wdown)             GEMMd  [12544,768]x[768,128]
//   out = [h | sd] @ [w2 ; wup] + b2      GEMM2  [12544,3200]x[3200,768]
//
// R12 = R11 (dbuf win: 333->309, VALUBusy 49->29) + GEMM1 TM=256:
//   staged-byte accounting (925 MB through L2/L3 in 105 us ~ 8.8 TB/s) says
//   GEMM1 is staging-stream-bound. TM=256 (512-thr block, 8 waves 4x2, wave
//   tile still 64x64 so VGPR ~unchanged) cuts staged bytes 25% and allows
//   3 resident blocks/CU. Grid (24,49) keeps the proven width-24 order.
//   GEMM2 (624-block XCD swizzle, TM=128) and GEMMd frozen.

#define NTOK   12544
#define CDIM   768
#define HIDDIM 3072
#define KBIG   3200

typedef __attribute__((ext_vector_type(8))) short bf16x8;
typedef __attribute__((ext_vector_type(4))) float f32x4;

#define GLOBAL_AS(p) ((const __attribute__((address_space(1))) void*)(p))
#define LDS_AS(p)    ((__attribute__((address_space(3))) void*)(p))

__device__ inline unsigned short f2bf(float f) {
    unsigned int x = __float_as_uint(f);
    x += 0x7fffu + ((x >> 16) & 1u);   // RNE
    return (unsigned short)(x >> 16);
}

// tanh-form GELU, branch-free; max |err| ~4.3e-4 vs exact erf form.
__device__ inline float gelu_fast(float x) {
    float x3 = x * x * x;
    float u2 = 1.5957691216057308f * x + 0.07135481627260025f * x3;
    float e = __expf(-u2);
    return x * __builtin_amdgcn_rcpf(1.0f + e);
}

// ---------------- fused prep: cast_x + 3 transposes (64x64) + pack_wdown -------
__global__ void __launch_bounds__(256) prep_kernel(
        const float* __restrict__ x, const float* __restrict__ w1,
        const float* __restrict__ w2, const float* __restrict__ wup,
        const float* __restrict__ wdn,
        unsigned short* __restrict__ xb, unsigned short* __restrict__ w1t,
        unsigned short* __restrict__ B2t, unsigned short* __restrict__ wdt) {
    __shared__ float tile[64][65];
    const int b = blockIdx.x, tid = threadIdx.x;
    if (b < 9408) {                      // cast x -> bf16, float4->ushort4
        int i = b * 256 + tid;
        float4 v = ((const float4*)x)[i];
        ushort4 o;
        o.x = f2bf(v.x); o.y = f2bf(v.y); o.z = f2bf(v.z); o.w = f2bf(v.w);
        ((ushort4*)xb)[i] = o;
        return;
    }
    if (b < 10584) {                     // 64x64 transpose tiles
        const float* in; unsigned short* outp; int Ccols, out_ld, out_off, bx, by;
        if (b < 9984)       { int t = b - 9408;  in = w1;  outp = w1t; Ccols = 3072; out_ld = 768;  out_off = 0;    bx = t % 48; by = t / 48; }
        else if (b < 10560) { int t = b - 9984;  in = w2;  outp = B2t; Ccols = 768;  out_ld = 3200; out_off = 0;    bx = t % 12; by = t / 12; }
        else                { int t = b - 10560; in = wup; outp = B2t; Ccols = 768;  out_ld = 3200; out_off = 3072; bx = t % 12; by = t / 12; }
        const int c0 = bx * 64, r0 = by * 64;
        #pragma unroll
        for (int p = 0; p < 4; ++p) {
            int idx = p * 256 + tid;
            int r = idx >> 4, c4 = (idx & 15) * 4;
            float4 v = *(const float4*)&in[(size_t)(r0 + r) * Ccols + c0 + c4];
            tile[r][c4 + 0] = v.x; tile[r][c4 + 1] = v.y;
            tile[r][c4 + 2] = v.z; tile[r][c4 + 3] = v.w;
        }
        __syncthreads();
        #pragma unroll
        for (int p = 0; p < 2; ++p) {
            int u = p * 256 + tid;
            int cc = u >> 3, r8 = (u & 7) * 8;
            uint4 pk;
            pk.x = (unsigned)f2bf(tile[r8 + 0][cc]) | ((unsigned)f2bf(tile[r8 + 1][cc]) << 16);
            pk.y = (unsigned)f2bf(tile[r8 + 2][cc]) | ((unsigned)f2bf(tile[r8 + 3][cc]) << 16);
            pk.z = (unsigned)f2bf(tile[r8 + 4][cc]) | ((unsigned)f2bf(tile[r8 + 5][cc]) << 16);
            pk.w = (unsigned)f2bf(tile[r8 + 6][cc]) | ((unsigned)f2bf(tile[r8 + 7][cc]) << 16);
            *(uint4*)&outp[(size_t)(c0 + cc) * out_ld + out_off + r0 + r8] = pk;
        }
        return;
    }
    {   // pack_wdown: wdt[j][c] = wdown[e][c][r], j = e*16+r
        int idx = (b - 10584) * 256 + tid;
        int j = idx / 768, c = idx - j * 768;
        int e = j >> 4, r = j & 15;
        wdt[idx] = f2bf(wdn[((size_t)e * 768 + c) * 16 + r]);
    }
}

// ---- MFMA GEMM, C = A * Bt^T, TM x 128 tile, BK=32, LDS double-buffer --------
// TM=128: 256 thr, 4 waves (2x2).  TM=256: 512 thr, 8 waves (4x2).
// Wave tile is always 64x64 (acc 4x4) -> VGPR identical across TM.
// EPI 0: gelu(acc + b1[n]) -> bf16 Ap[m*3200 + n]
// EPI 1: wt[m, n>>4]*gelu(acc) -> bf16 Ap[m*3200 + 3072 + n]
// EPI 2: acc + b2[n] -> f32 out[m*768 + n]  (1-D grid + XCD swizzle)

template <int EPI, int TM>
__global__ void __launch_bounds__(TM * 2)
gemm_bt_kernel(const unsigned short* __restrict__ A, int lda,
               const unsigned short* __restrict__ Bt, int ldb,
               int kIters,
               const float* __restrict__ bias,
               unsigned short* __restrict__ apOut,
               float* __restrict__ fOut,
               const int* __restrict__ tki,
               const float* __restrict__ tkp) {
    constexpr int NT    = TM * 2;          // threads
    constexpr int ABUF  = TM * 32;         // elems per A buffer
    constexpr int BBUF  = 128 * 32;        // elems per B buffer
    __shared__ __align__(16) unsigned short As[2 * ABUF];
    __shared__ __align__(16) unsigned short Bs[2 * BBUF];

    int bx, by;
    if (EPI == 2) {
        // 624 blocks; same-m-row blocks share L&7 -> same XCD, consecutive.
        int L = blockIdx.x;
        int k = L & 7, t = L >> 3;
        bx = t % 6;
        by = (t / 6) * 8 + k;
        if (by >= NTOK / 128) return;      // block-uniform, pre-barrier safe
    } else {
        bx = blockIdx.x;
        by = blockIdx.y;
    }

    const int tid  = threadIdx.x;
    const int wave = tid >> 6;
    const int lane = tid & 63;
    const int m0 = by * TM;
    const int n0 = bx * 128;
    const int wm = (wave >> 1) * 64;
    const int wn = (wave & 1) * 64;
    const int row16 = lane & 15;
    const int quad  = lane >> 4;
    const int kch   = quad * 8;

    f32x4 acc[4][4] = {};

    // Staging (proven layout): chunk ci covers a [rows][32] tile row-major
    // (row = ci>>2, kcol = (ci&3)*8); source contiguous in lane order; LDS
    // dest = wave-uniform base + lane*16B. 64-B row stride (2-bank, free).
    // A: 2 passes of NT chunks (rows step NT/4). B: 512 chunks -> 512/NT passes.
    const int r_s = tid >> 2;
    const int c_s = (tid & 3) * 8;
    const size_t aRow0 = (size_t)(m0 + r_s) * lda + c_s;
    const size_t aRow1 = aRow0 + (size_t)(NT / 4) * lda;
    const size_t bRow0 = (size_t)(n0 + r_s) * ldb + c_s;
    const size_t bRow1 = bRow0 + (size_t)64 * ldb;       // used only if TM==128
    unsigned short* asB0 = &As[(wave * 64) * 8];
    unsigned short* asB1 = &As[(NT + wave * 64) * 8];
    unsigned short* bsB0 = &Bs[(wave * 64) * 8];
    unsigned short* bsB1 = &Bs[(256 + wave * 64) * 8];

    // prologue: prefetch tile 0 into buffer 0
    {
        __builtin_amdgcn_global_load_lds(GLOBAL_AS(A + aRow0), LDS_AS(asB0), 16, 0, 0);
        __builtin_amdgcn_global_load_lds(GLOBAL_AS(A + aRow1), LDS_AS(asB1), 16, 0, 0);
        __builtin_amdgcn_global_load_lds(GLOBAL_AS(Bt + bRow0), LDS_AS(bsB0), 16, 0, 0);
        if (TM == 128)
            __builtin_amdgcn_global_load_lds(GLOBAL_AS(Bt + bRow1), LDS_AS(bsB1), 16, 0, 0);
    }

    for (int kt = 0; kt < kIters; ++kt) {
        // barrier: compiler-emitted vmcnt(0)+lgkmcnt(0) drain guarantees
        // buf[kt&1] landed AND all waves done reading buf[(kt+1)&1].
        __syncthreads();

        if (kt + 1 < kIters) {             // prefetch kt+1 into alternate buffer
            const int k1 = (kt + 1) * 32;
            const int pa = ((kt + 1) & 1) * ABUF;
            const int pb = ((kt + 1) & 1) * BBUF;
            __builtin_amdgcn_global_load_lds(GLOBAL_AS(A + aRow0 + k1), LDS_AS(asB0 + pa), 16, 0, 0);
            __builtin_amdgcn_global_load_lds(GLOBAL_AS(A + aRow1 + k1), LDS_AS(asB1 + pa), 16, 0, 0);
            __builtin_amdgcn_global_load_lds(GLOBAL_AS(Bt + bRow0 + k1), LDS_AS(bsB0 + pb), 16, 0, 0);
            if (TM == 128)
                __builtin_amdgcn_global_load_lds(GLOBAL_AS(Bt + bRow1 + k1), LDS_AS(bsB1 + pb), 16, 0, 0);
        }

        const int ca = (kt & 1) * ABUF;
        const int cb = (kt & 1) * BBUF;
        bf16x8 af[4], bfr[4];
        #pragma unroll
        for (int mi = 0; mi < 4; ++mi)
            af[mi] = *(const bf16x8*)&As[ca + (wm + mi * 16 + row16) * 32 + kch];
        #pragma unroll
        for (int ni = 0; ni < 4; ++ni)
            bfr[ni] = *(const bf16x8*)&Bs[cb + (wn + ni * 16 + row16) * 32 + kch];

        #pragma unroll
        for (int mi = 0; mi < 4; ++mi)
            #pragma unroll
            for (int ni = 0; ni < 4; ++ni)
                acc[mi][ni] = __builtin_amdgcn_mfma_f32_16x16x32_bf16(
                    af[mi], bfr[ni], acc[mi][ni], 0, 0, 0);
    }

    // epilogue (R8-exact): lane holds col = row16 (+16*ni), rows quad*4 + i
    #pragma unroll
    for (int mi = 0; mi < 4; ++mi) {
        #pragma unroll
        for (int i = 0; i < 4; ++i) {
            const int m = m0 + wm + mi * 16 + quad * 4 + i;
            int i0 = 0, i1 = 0; float p0 = 0.f, p1 = 0.f;
            if (EPI == 1) {
                i0 = tki[m * 2]; i1 = tki[m * 2 + 1];
                p0 = tkp[m * 2]; p1 = tkp[m * 2 + 1];
            }
            #pragma unroll
            for (int ni = 0; ni < 4; ++ni) {
                const int ncol = n0 + wn + ni * 16 + row16;
                float v = acc[mi][ni][i];
                if (EPI == 0) {
                    v = gelu_fast(v + bias[ncol]);
                    apOut[(size_t)m * KBIG + ncol] = f2bf(v);
                } else if (EPI == 1) {
                    const int e = ncol >> 4;
                    float wt = (i0 == e ? p0 : 0.f) + (i1 == e ? p1 : 0.f);
                    v = gelu_fast(v) * wt;
                    apOut[(size_t)m * KBIG + 3072 + ncol] = f2bf(v);
                } else {
                    fOut[(size_t)m * CDIM + ncol] = v + bias[ncol];
                }
            }
        }
    }
}

// ---------------- launch ----------------

extern "C" void kernel_launch(void* const* d_in, const int* in_sizes, int n_in,
                              void* d_out, int out_size, void* d_ws, size_t ws_size,
                              hipStream_t stream) {
    const float* x   = (const float*)d_in[0];
    const float* tkp = (const float*)d_in[1];
    const int*   tki = (const int*)d_in[2];
    const float* w1  = (const float*)d_in[3];
    const float* b1  = (const float*)d_in[4];
    const float* w2  = (const float*)d_in[5];
    const float* b2  = (const float*)d_in[6];
    const float* wdn = (const float*)d_in[7];
    const float* wup = (const float*)d_in[8];
    float* out = (float*)d_out;

    unsigned short* xb  = (unsigned short*)d_ws;
    unsigned short* w1t = xb  + (size_t)NTOK * CDIM;      // 3072 x 768
    unsigned short* B2t = w1t + (size_t)HIDDIM * CDIM;    // 768 x 3200
    unsigned short* wdt = B2t + (size_t)CDIM * KBIG;      // 128 x 768
    unsigned short* Ap  = wdt + (size_t)128 * CDIM;       // 12544 x 3200

    prep_kernel<<<dim3(10968), 256, 0, stream>>>(x, w1, w2, wup, wdn,
                                                 xb, w1t, B2t, wdt);

    // GEMMd: sd -> Ap[:, 3072:3200] ; 98 blocks, TM=128
    gemm_bt_kernel<1, 128><<<dim3(1, NTOK / 128), 256, 0, stream>>>(
        xb, CDIM, wdt, CDIM, CDIM / 32, nullptr, Ap, nullptr, tki, tkp);
    // GEMM1: h -> Ap[:, 0:3072] ; TM=256, grid (24, 49), 512 threads
    gemm_bt_kernel<0, 256><<<dim3(HIDDIM / 128, NTOK / 256), 512, 0, stream>>>(
        xb, CDIM, w1t, CDIM, CDIM / 32, b1, Ap, nullptr, nullptr, nullptr);
    // GEMM2: out = Ap @ B2t^T + b2 ; 624-block XCD-swizzled grid, TM=128
    gemm_bt_kernel<2, 128><<<dim3(624), 256, 0, stream>>>(
        Ap, KBIG, B2t, KBIG, KBIG / 32, b2, nullptr, out, nullptr, nullptr);
}